// Round 4
// baseline (339.252 us; speedup 1.0000x reference)
//
#include <hip/hip_runtime.h>

#define CIN 64
#define OC 128
#define HW 112
#define HWHW (HW*HW)          // 12544
#define NIMG 32

// ws layout (elems of bf16/ushort):
//   [0, +73728): weights bf16, layout [tap][k-half][128 o][32 c]
// (x no longer staged through ws -- conv reads fp32 NCHW x directly)

#define ROWE (114*64)                   // LDS row slot: 114 cols (+-1 pad) x 64c

typedef __attribute__((ext_vector_type(8))) short short8;
typedef __attribute__((ext_vector_type(4))) float floatx4;

__device__ inline unsigned short f2bf(float f) {
    unsigned u = __float_as_uint(f);
    u += 0x7fffu + ((u >> 16) & 1u);   // RNE
    return (unsigned short)(u >> 16);
}

// ---- Kernel 1: weights [O][C][3][3] fp32 -> [tap][c>>5][o][c&31] bf16 ----
__global__ __launch_bounds__(256) void xform_w(const float* __restrict__ wgt,
                                               unsigned short* __restrict__ ws16)
{
    const int idx = blockIdx.x * 256 + threadIdx.x;    // 0..73727
    const int c = idx & 63;
    const int o = (idx >> 6) & 127;
    const int t = idx >> 13;                           // 0..8
    const float v = wgt[(o * CIN + c) * 9 + t];
    ws16[((size_t)(t * 2 + (c >> 5)) * 128 + o) * 32 + (c & 31)] = f2bf(v);
}

// ---- Kernel 2: FUSED implicit-GEMM MFMA ----
// Single structural change vs round 3: x-transform fused into the conv's
// staging phase. Each block reads its 4 rows directly from fp32 NCHW x,
// transposing c<->w in registers (v_cvt_pk_bf16_f32) into the SAME
// XOR-swizzled [col][c] bf16 LDS layout the MFMA loop already consumes.
// Deletes xform_x's 102.8R+51.4W round-trip + its kernel elapsed + gap.
// Block: 256 thr = 4 waves; tile 224m(2 rows) x 128o; one barrier total.
__global__ __launch_bounds__(256, 2) void conv_fused(
    const float* __restrict__ x,
    const unsigned short* __restrict__ wgt16,
    const float* __restrict__ bias,
    float* __restrict__ out)
{
    __shared__ unsigned short sx[4 * ROWE];   // 58368 B -> 2 blocks/CU

    const int tid  = threadIdx.x;
    const int wave = tid >> 6;
    const int lane = tid & 63;
    const int lane_lo = lane & 15;
    const int lane_hi = lane >> 4;

    // XCD-chunked swizzle: 1792 = 8 XCDs x 224 consecutive tiles (4 whole
    // images each); halo-row re-reads (now fp32, 2x of 102.8 MB) hit the
    // same XCD's L2. 1792 % 8 == 0 -> bijective.
    const int bid0 = blockIdx.x;
    const int bid  = (bid0 & 7) * 224 + (bid0 >> 3);
    const int n   = bid / 56;
    const int rp  = bid % 56;
    const int h0  = rp * 2;

    // ---- fused stage: NCHW fp32 -> swizzled [col][c] bf16, 4 row slots ----
    // thread t: c-pair p = t&31 (c = 2p, c+1), quad-group g = t>>5.
    // Per (row, quad q): load float4 from planes c and c+1, cvt_pk to 4
    // dwords (lo=c, hi=c+1), scatter as ds_write_b32. Bank pattern: 64
    // lanes write 4B each, contiguous 128B per column slice -> <=2-way.
    {
        const int p    = tid & 31;
        const int g    = tid >> 5;           // 0..7
        const int c    = p * 2;
        const int cblk = p >> 2;             // c>>3
        const int crem = c & 7;              // even
        #pragma unroll 1
        for (int s = 0; s < 4; ++s) {
            const int hr = h0 + s - 1;
            unsigned short* rowb = sx + s * ROWE;
            if ((unsigned)hr < (unsigned)HW) {
                const float* xr = x + ((size_t)(n * CIN + c)) * HWHW + hr * HW;
                #pragma unroll
                for (int k = 0; k < 4; ++k) {
                    const int q = g + 8 * k;             // quad 0..27
                    if (q < 28) {
                        const float4 fa = *(const float4*)(xr + 4 * q);
                        const float4 fb = *(const float4*)(xr + HWHW + 4 * q);
                        #pragma unroll
                        for (int j = 0; j < 4; ++j) {
                            const int col = 4 * q + j + 1;   // stored col (pad +1)
                            const float sa = ((const float*)&fa)[j];
                            const float sb = ((const float*)&fb)[j];
                            unsigned d;
                            asm("v_cvt_pk_bf16_f32 %0, %1, %2"
                                : "=v"(d) : "v"(sa), "v"(sb));
                            // logical c-block cblk stored at slot cblk^(col&7)
                            *(unsigned*)(rowb + col * 64 +
                                         ((cblk ^ (col & 7)) << 3) + crem) = d;
                        }
                    }
                }
                // zero the two pad columns (stored cols 0 and 113)
                if (tid < 8)       *(uint4*)(rowb + tid * 8) = (uint4){0,0,0,0};
                else if (tid < 16) *(uint4*)(rowb + 113*64 + (tid - 8) * 8) = (uint4){0,0,0,0};
            } else {
                #pragma unroll
                for (int k = 0; k < 4; ++k) {
                    const int e = tid + k * 256;         // 912 x 16B chunks
                    if (e < ROWE / 8) *(uint4*)(rowb + e * 8) = (uint4){0,0,0,0};
                }
            }
        }
    }
    __syncthreads();   // drains lgkmcnt (ds_writes); slots 0..3 ready

    floatx4 acc[7][4];
    #pragma unroll
    for (int mt = 0; mt < 7; ++mt)
        #pragma unroll
        for (int ot = 0; ot < 4; ++ot)
            acc[mt][ot] = (floatx4){0.f, 0.f, 0.f, 0.f};

    const unsigned short* wA = wgt16;
    const int row_idx = wave >> 1;          // which of the 2 output rows
    const int o0 = (wave & 1) * 64;
    const int aL = (o0 + lane_lo) * 32 + lane_hi * 8;  // lane offset in [128o][32c]

    // A-frags double-buffered across taps (weights are L1/L2-hot)
    short8 a[2][2][4];
    #pragma unroll
    for (int k01 = 0; k01 < 2; ++k01)
        #pragma unroll
        for (int ot = 0; ot < 4; ++ot)
            a[0][k01][ot] = *(const short8*)(wA + k01 * 4096 + ot * 512 + aL);

    #pragma unroll
    for (int tap = 0; tap < 9; ++tap) {
        const int dh = tap / 3 - 1;
        const int dw = tap % 3 - 1;
        const int cur = tap & 1, nxt = cur ^ 1;
        if (tap < 8) {
            #pragma unroll
            for (int k01 = 0; k01 < 2; ++k01)
                #pragma unroll
                for (int ot = 0; ot < 4; ++ot)
                    a[nxt][k01][ot] = *(const short8*)(
                        wA + ((tap + 1) * 2 + k01) * 4096 + ot * 512 + aL);
        }
        const int colL = lane_lo + dw + 1;                 // stored col for mt=0
        const unsigned short* sb = sx + (row_idx + 1 + dh) * ROWE + colL * 64;
        const int sw0 = (lane_hi ^ (colL & 7)) * 8;        // k01=0 swizzle
        const int sw1 = ((lane_hi + 4) ^ (colL & 7)) * 8;  // k01=1 swizzle

        #pragma unroll
        for (int mt = 0; mt < 7; ++mt) {
            const short8 b0 = *(const short8*)(sb + mt * 1024 + sw0);
            const short8 b1 = *(const short8*)(sb + mt * 1024 + sw1);
            #pragma unroll
            for (int ot = 0; ot < 4; ++ot)
                acc[mt][ot] = __builtin_amdgcn_mfma_f32_16x16x32_bf16(
                    a[cur][0][ot], b0, acc[mt][ot], 0, 0, 0);
            #pragma unroll
            for (int ot = 0; ot < 4; ++ot)
                acc[mt][ot] = __builtin_amdgcn_mfma_f32_16x16x32_bf16(
                    a[cur][1][ot], b1, acc[mt][ot], 0, 0, 0);
        }
    }

    // ---- epilogue: D col = m (lane_lo), row = o_rel = lane_hi*4 + i ----
    const int h = h0 + row_idx;
    #pragma unroll
    for (int ot = 0; ot < 4; ++ot) {
        const int ob = o0 + ot * 16 + lane_hi * 4;
        const float4 bv = *(const float4*)(bias + ob);
        #pragma unroll
        for (int mt = 0; mt < 7; ++mt) {
            const int w = mt * 16 + lane_lo;
            float* op = out + ((size_t)(n * OC + ob) * HW + h) * HW + w;
            op[0]        = acc[mt][ot].x + bv.x;
            op[HWHW]     = acc[mt][ot].y + bv.y;
            op[2 * HWHW] = acc[mt][ot].z + bv.z;
            op[3 * HWHW] = acc[mt][ot].w + bv.w;
        }
    }
}

extern "C" void kernel_launch(void* const* d_in, const int* in_sizes, int n_in,
                              void* d_out, int out_size, void* d_ws, size_t ws_size,
                              hipStream_t stream) {
    const float* x    = (const float*)d_in[0];
    const float* wgt  = (const float*)d_in[1];
    const float* bias = (const float*)d_in[2];
    float* out = (float*)d_out;
    unsigned short* ws16 = (unsigned short*)d_ws;

    hipLaunchKernelGGL(xform_w, dim3(288), dim3(256), 0, stream, wgt, ws16);
    hipLaunchKernelGGL(conv_fused, dim3(NIMG * 56), dim3(256), 0, stream,
                       x, ws16, bias, out);
}

// Round 5
// 336.201 us; speedup vs baseline: 1.0091x; 1.0091x over previous
//
#include <hip/hip_runtime.h>

#define CIN 64
#define OC 128
#define HW 112
#define HWHW (HW*HW)          // 12544
#define NIMG 32

// ws layout (elems of bf16/ushort):
//   [0, XN_ELEMS): x_nhwc bf16  [32][112][112][64]
//   [WT_OFF_EL, +73728): weights bf16, layout [tap][k-half][128 o][32 c]
#define XN_ELEMS (NIMG*HWHW*CIN)        // 25,690,112
#define WT_OFF_EL (XN_ELEMS + 128)

#define ROWE (114*64)                   // LDS row slot: 114 cols (+-1 pad) x 64c

typedef __attribute__((ext_vector_type(8))) short short8;
typedef __attribute__((ext_vector_type(4))) float floatx4;

// counted waits (T4): literal immediates, memory-clobber pins load order
#define WAIT_V8  asm volatile("s_waitcnt vmcnt(8) lgkmcnt(0)" ::: "memory")
#define WAIT_V6  asm volatile("s_waitcnt vmcnt(6) lgkmcnt(0)" ::: "memory")
#define WAIT_V0  asm volatile("s_waitcnt vmcnt(0) lgkmcnt(0)" ::: "memory")
#define WAIT_V19 asm volatile("s_waitcnt vmcnt(19)" ::: "memory")
#define WAIT_V40 asm volatile("s_waitcnt vmcnt(40)" ::: "memory")

__device__ inline unsigned short f2bf(float f) {
    unsigned u = __float_as_uint(f);
    u += 0x7fffu + ((u >> 16) & 1u);   // RNE
    return (unsigned short)(u >> 16);
}

__device__ inline void async16(const unsigned short* g, unsigned short* l) {
    __builtin_amdgcn_global_load_lds(
        (const __attribute__((address_space(1))) void*)g,
        (__attribute__((address_space(3))) void*)l, 16, 0, 0);
}

// ---- Kernel 1: x NCHW fp32 -> NHWC bf16 (LDS tile transpose), per (n,h) ----
__global__ __launch_bounds__(256) void xform_x(const float* __restrict__ x,
                                               unsigned short* __restrict__ xws)
{
    __shared__ float s[HW * (CIN + 1)];
    const int tid = threadIdx.x;
    const int n = blockIdx.x / HW;
    const int h = blockIdx.x % HW;

    const float* xp = x + (size_t)n * CIN * HWHW + h * HW;
    for (int idx = tid; idx < CIN * HW; idx += 256) {
        int c = idx / HW;
        int w = idx - c * HW;
        s[w * (CIN + 1) + c] = xp[c * HWHW + w];
    }
    __syncthreads();

    unsigned short* op = xws + ((size_t)(n * HW + h)) * HW * CIN;
    for (int idx = tid; idx < (CIN * HW) / 8; idx += 256) {
        int w  = idx >> 3;
        int c0 = (idx & 7) * 8;
        union { unsigned short us[8]; uint4 v; } u;
        #pragma unroll
        for (int j = 0; j < 8; ++j)
            u.us[j] = f2bf(s[w * (CIN + 1) + c0 + j]);
        *(uint4*)(op + w * CIN + c0) = u.v;
    }
}

// ---- Kernel 1b: weights [O][C][3][3] fp32 -> [tap][c>>5][o][c&31] bf16 ----
__global__ __launch_bounds__(256) void xform_w(const float* __restrict__ wgt,
                                               unsigned short* __restrict__ ws16)
{
    const int idx = blockIdx.x * 256 + threadIdx.x;    // 0..73727
    const int c = idx & 63;
    const int o = (idx >> 6) & 127;
    const int t = idx >> 13;                           // 0..8
    const float v = wgt[(o * CIN + c) * 9 + t];
    ws16[WT_OFF_EL + ((size_t)(t * 2 + (c >> 5)) * 128 + o) * 32 + (c & 31)] = f2bf(v);
}

// ---- Kernel 2: implicit-GEMM MFMA, counted-vmcnt staging pipeline ----
// r3 structure (same grid 1792, same 4 slots, same loads) with the single
// barrier's full vmcnt(0) drain replaced by counted waits:
//   issue order per wave:  A-taps0-2 (24 ld) | staging slot-major (16/12 ld)
//   barrier1: vmcnt(8/6)  -> slots 0,1 ready; slots 2,3 IN FLIGHT
//   taps 0-2 (dh=-1) compute over slots 0,1 while slots 2,3 land
//   tap3 checkpoint: vmcnt(19) -> slot 2; tap6: vmcnt(40) -> slot 3
// Boundary blocks (rp=0,55; 3.6%) use a conservative vmcnt(0) path.
__global__ __launch_bounds__(256, 2) void conv_mfma(
    const unsigned short* __restrict__ ws16,
    const float* __restrict__ bias,
    float* __restrict__ out)
{
    __shared__ unsigned short sx[4 * ROWE];   // 58368 B

    const int tid  = threadIdx.x;
    const int wave = tid >> 6;
    const int lane = tid & 63;
    const int lane_lo = lane & 15;
    const int lane_hi = lane >> 4;

    // XCD-chunked swizzle (kept: -6.6% normalized, r3 vs r0)
    const int bid0 = blockIdx.x;
    const int bid  = (bid0 & 7) * 224 + (bid0 >> 3);
    const int n   = bid / 56;
    const int rp  = bid % 56;
    const int h0  = rp * 2;
    const bool interior = (rp > 0) && (rp < 55);   // all 4 slots are valid rows

    const unsigned short* wA = ws16 + WT_OFF_EL;
    const int row_idx = wave >> 1;
    const int o0 = (wave & 1) * 64;
    const int aL = (o0 + lane_lo) * 32 + lane_hi * 8;

    // ---- A-preload taps 0..2 FIRST (oldest 24 loads; keeps the compiler's
    // FIFO vmcnt for A-uses from forcing the staging drain in taps 0-2) ----
    short8 a[3][2][4];
    #pragma unroll
    for (int t = 0; t < 3; ++t)
        #pragma unroll
        for (int k01 = 0; k01 < 2; ++k01)
            #pragma unroll
            for (int ot = 0; ot < 4; ++ot)
                a[t][k01][ot] = *(const short8*)(
                    wA + (t * 2 + k01) * 4096 + ot * 512 + aL);

    asm volatile("" ::: "memory");   // pin: preload issues before staging

    // ---- staging: chunk-split across waves, SLOT-MAJOR issue order ----
    // wave w loads chunks j in {w, w+4, w+8, w+12} (<14) of every slot.
    {
        const int grp = lane >> 3;
        const int sub = lane & 7;
        const int swz = sub ^ ((1 + grp) & 7);
        #pragma unroll
        for (int s = 0; s < 4; ++s) {
            const int hr = h0 + s - 1;
            unsigned short* rowb = sx + s * ROWE;
            if ((unsigned)hr < (unsigned)HW) {
                const unsigned short* gl = ws16 +
                    ((size_t)(n * HW + hr)) * HW * CIN + grp * 64 + swz * 8;
                #pragma unroll
                for (int k = 0; k < 4; ++k) {
                    const int j = wave + 4 * k;
                    if (j < 14) async16(gl + j * 512, rowb + (1 + j * 8) * 64);
                }
            } else {
                #pragma unroll
                for (int k = 0; k < 4; ++k) {
                    const int j = wave + 4 * k;
                    if (j < 14)
                        *(uint4*)(rowb + (1 + j * 8) * 64 + lane * 8) = (uint4){0,0,0,0};
                }
            }
        }
        // pad columns (stored cols 0,113): wave w owns slot w
        unsigned short* rowb = sx + wave * ROWE;
        if (lane < 8)       *(uint4*)(rowb + lane * 8) = (uint4){0,0,0,0};
        else if (lane < 16) *(uint4*)(rowb + 113*64 + (lane - 8) * 8) = (uint4){0,0,0,0};
    }

    // ---- barrier1: slots 0,1 ready; slots 2,3 (8/6 newest) stay in flight ----
    if (interior) { if (wave < 2) { WAIT_V8; } else { WAIT_V6; } }
    else          { WAIT_V0; }
    __builtin_amdgcn_s_barrier();
    __builtin_amdgcn_sched_barrier(0);

    floatx4 acc[7][4];
    #pragma unroll
    for (int mt = 0; mt < 7; ++mt)
        #pragma unroll
        for (int ot = 0; ot < 4; ++ot)
            acc[mt][ot] = (floatx4){0.f, 0.f, 0.f, 0.f};

    #pragma unroll
    for (int tap = 0; tap < 9; ++tap) {
        if (tap == 3) {   // need slot 2 (dh=0)
            if (interior) { WAIT_V19; } else { WAIT_V0; }
            __builtin_amdgcn_s_barrier();
            __builtin_amdgcn_sched_barrier(0);
        }
        if (tap == 6) {   // need slot 3 (dh=+1)
            if (interior) { WAIT_V40; } else { WAIT_V0; }
            __builtin_amdgcn_s_barrier();
            __builtin_amdgcn_sched_barrier(0);
        }
        const int dh = tap / 3 - 1;
        const int dw = tap % 3 - 1;
        // prefetch tap+2 into the buffer freed at tap-1 (distance-2, 3 bufs)
        if (tap >= 1 && tap <= 6) {
            #pragma unroll
            for (int k01 = 0; k01 < 2; ++k01)
                #pragma unroll
                for (int ot = 0; ot < 4; ++ot)
                    a[(tap + 2) % 3][k01][ot] = *(const short8*)(
                        wA + ((tap + 2) * 2 + k01) * 4096 + ot * 512 + aL);
        }
        const int colL = lane_lo + dw + 1;
        const unsigned short* sb = sx + (row_idx + 1 + dh) * ROWE + colL * 64;
        const int sw0 = (lane_hi ^ (colL & 7)) * 8;
        const int sw1 = ((lane_hi + 4) ^ (colL & 7)) * 8;

        #pragma unroll
        for (int mt = 0; mt < 7; ++mt) {
            const short8 b0 = *(const short8*)(sb + mt * 1024 + sw0);
            const short8 b1 = *(const short8*)(sb + mt * 1024 + sw1);
            #pragma unroll
            for (int ot = 0; ot < 4; ++ot)
                acc[mt][ot] = __builtin_amdgcn_mfma_f32_16x16x32_bf16(
                    a[tap % 3][0][ot], b0, acc[mt][ot], 0, 0, 0);
            #pragma unroll
            for (int ot = 0; ot < 4; ++ot)
                acc[mt][ot] = __builtin_amdgcn_mfma_f32_16x16x32_bf16(
                    a[tap % 3][1][ot], b1, acc[mt][ot], 0, 0, 0);
        }
    }

    // ---- epilogue: D col = m (lane_lo), row = o_rel = lane_hi*4 + i ----
    const int h = h0 + row_idx;
    #pragma unroll
    for (int ot = 0; ot < 4; ++ot) {
        const int ob = o0 + ot * 16 + lane_hi * 4;
        const float4 bv = *(const float4*)(bias + ob);
        #pragma unroll
        for (int mt = 0; mt < 7; ++mt) {
            const int w = mt * 16 + lane_lo;
            float* op = out + ((size_t)(n * OC + ob) * HW + h) * HW + w;
            op[0]        = acc[mt][ot].x + bv.x;
            op[HWHW]     = acc[mt][ot].y + bv.y;
            op[2 * HWHW] = acc[mt][ot].z + bv.z;
            op[3 * HWHW] = acc[mt][ot].w + bv.w;
        }
    }
}

extern "C" void kernel_launch(void* const* d_in, const int* in_sizes, int n_in,
                              void* d_out, int out_size, void* d_ws, size_t ws_size,
                              hipStream_t stream) {
    const float* x    = (const float*)d_in[0];
    const float* wgt  = (const float*)d_in[1];
    const float* bias = (const float*)d_in[2];
    float* out = (float*)d_out;
    unsigned short* ws16 = (unsigned short*)d_ws;

    hipLaunchKernelGGL(xform_x, dim3(NIMG * HW), dim3(256), 0, stream, x, ws16);
    hipLaunchKernelGGL(xform_w, dim3(288), dim3(256), 0, stream, wgt, ws16);
    hipLaunchKernelGGL(conv_mfma, dim3(NIMG * 56), dim3(256), 0, stream,
                       ws16, bias, out);
}